// Round 1
// baseline (1410.632 us; speedup 1.0000x reference)
//
#include <hip/hip_runtime.h>
#include <stdint.h>

#define M_ROWS 8192
#define K_DIM  4096
#define N_DIM  11008

#define BM 128
#define BN 128
#define BK 64
#define KSTEPS (K_DIM / BK)   // 64
#define MBLKS  (M_ROWS / BM)  // 64
#define NBLKS  (N_DIM / BN)   // 86
#define NWG    (MBLKS * NBLKS) // 5504  (divisible by 8 -> simple XCD swizzle is bijective)

typedef __attribute__((ext_vector_type(4))) float          f32x4;
typedef __attribute__((ext_vector_type(8))) __bf16         bf16x8;
typedef __attribute__((ext_vector_type(4))) int            i32x4;
typedef __attribute__((ext_vector_type(8))) unsigned short u16x8;

__constant__ float NF4_TBL[16] = {
    -1.0f, -0.6961928009986877f, -0.5250730514526367f, -0.39491748809814453f,
    -0.28444138169288635f, -0.18477343022823334f, -0.10644006729125977f,
    -0.029167551919817924f, 0.0f, 0.07958029955625534f, 0.16093020141124725f,
    0.24611230194568634f, 0.33791524171829224f, 0.44070982933044434f,
    0.5626170039176941f, 0.7229568362236023f};

__device__ __forceinline__ unsigned short f2bf(float f) {
  uint32_t u = __float_as_uint(f);
  u += 0x7fffu + ((u >> 16) & 1u);   // round-to-nearest-even
  return (unsigned short)(u >> 16);
}

// global -> LDS direct copy, 16B per lane. LDS dest must be wave-uniform;
// HW writes dest + lane*16. Integer-cast route (CK pattern): low 32 bits of a
// flat LDS address are the LDS byte offset (aperture is 4GB-aligned).
__device__ __forceinline__ void gload_lds16(const void* g, const void* l) {
  __builtin_amdgcn_global_load_lds(
      (const __attribute__((address_space(1))) void*)(uintptr_t)g,
      (__attribute__((address_space(3))) void*)(uint32_t)(uintptr_t)l,
      16, 0, 0);
}

// ---------------- prep kernel 1: x fp32 -> bf16 ----------------
__global__ void convert_x_kernel(const float* __restrict__ x,
                                 unsigned short* __restrict__ xb) {
  const long n8 = (long)M_ROWS * K_DIM / 8;
  for (long t = (long)blockIdx.x * blockDim.x + threadIdx.x; t < n8;
       t += (long)gridDim.x * blockDim.x) {
    const float* p = x + t * 8;
    f32x4 v0 = *(const f32x4*)p;
    f32x4 v1 = *(const f32x4*)(p + 4);
    u16x8 o;
    o[0] = f2bf(v0[0]); o[1] = f2bf(v0[1]); o[2] = f2bf(v0[2]); o[3] = f2bf(v0[3]);
    o[4] = f2bf(v1[0]); o[5] = f2bf(v1[1]); o[6] = f2bf(v1[2]); o[7] = f2bf(v1[3]);
    *(u16x8*)(xb + t * 8) = o;
  }
}

// ---------------- prep kernel 2: NF4 dequant W -> bf16 ----------------
__global__ void dequant_w_kernel(const int* __restrict__ qw,
                                 const int* __restrict__ qs,
                                 const float* __restrict__ qf,
                                 const float* __restrict__ mean,
                                 unsigned short* __restrict__ wb) {
  __shared__ float tbl[16];
  if (threadIdx.x < 16) tbl[threadIdx.x] = NF4_TBL[threadIdx.x];
  __syncthreads();
  const float mu = mean[0];
  const long n8 = (long)N_DIM * K_DIM / 8;
  for (long t = (long)blockIdx.x * blockDim.x + threadIdx.x; t < n8;
       t += (long)gridDim.x * blockDim.x) {
    long f = t * 8;                    // 8 elems, all inside one 64-elem block
    int  g = (int)(f >> 6);            // quant block index
    float s = (float)qs[g] / qf[g >> 8] + mu;
    i32x4 q0 = *(const i32x4*)(qw + f);
    i32x4 q1 = *(const i32x4*)(qw + f + 4);
    u16x8 o;
    o[0] = f2bf(tbl[q0[0]] * s); o[1] = f2bf(tbl[q0[1]] * s);
    o[2] = f2bf(tbl[q0[2]] * s); o[3] = f2bf(tbl[q0[3]] * s);
    o[4] = f2bf(tbl[q1[0]] * s); o[5] = f2bf(tbl[q1[1]] * s);
    o[6] = f2bf(tbl[q1[2]] * s); o[7] = f2bf(tbl[q1[3]] * s);
    *(u16x8*)(wb + f) = o;
  }
}

// ---------------- GEMM: C[M,N] = A[M,K] * B[N,K]^T, bf16 MFMA ----------------
// MODE 0: A,B pre-converted bf16 in workspace, staged via global_load_lds.
// MODE 1: fallback, no workspace: reg-stage x (fp32->bf16) and qweight
//         (NF4 dequant->bf16) into LDS on the fly.
template <int MODE>
__global__ __launch_bounds__(256) void gemm_nf4(
    const unsigned short* __restrict__ Abf, const unsigned short* __restrict__ Bbf,
    const float* __restrict__ Xf, const int* __restrict__ qw,
    const int* __restrict__ qs, const float* __restrict__ qf,
    const float* __restrict__ meanp, float* __restrict__ C) {
  __shared__ unsigned short As[BM * BK];   // [128][64] bf16, 16 KB
  __shared__ unsigned short Bs[BN * BK];   // [128][64] bf16, 16 KB
  __shared__ float tbl[16];

  const int tid = threadIdx.x;
  if (MODE == 1 && tid < 16) tbl[tid] = NF4_TBL[tid];
  const float mu = (MODE == 1) ? meanp[0] : 0.0f;

  // XCD-aware bijective swizzle: 64 consecutive wg share one B panel (1 MB -> L2)
  const int wg = ((int)blockIdx.x & 7) * (NWG / 8) + ((int)blockIdx.x >> 3);
  const int mb = wg % MBLKS;
  const int nb = wg / MBLKS;
  const int m0 = mb * BM, n0 = nb * BN;

  const int wid = tid >> 6, lane = tid & 63;
  const int wr = wid >> 1, wc = wid & 1;       // 2x2 waves, each 64x64 output
  const int r16 = lane & 15, hi = lane >> 4;   // fragment coords
  const int sub = lane >> 3;                   // staging: row-within-chunk
  const int kk  = (lane & 7) * 8;              // staging: k-offset (bf16 elems)

  f32x4 acc[4][4] = {};

  for (int t = 0; t < KSTEPS; ++t) {
    const int k0 = t * BK;
    __syncthreads();                 // previous tile's compute done
    if constexpr (MODE == 0) {
#pragma unroll
      for (int i = 0; i < 4; ++i) {  // A tile: 4 chunks/wave x 1KB
        int c = wid * 4 + i;
        int row = c * 8 + sub;
        gload_lds16(Abf + (long)(m0 + row) * K_DIM + k0 + kk, &As[c * 512]);
      }
#pragma unroll
      for (int i = 0; i < 4; ++i) {  // B tile
        int c = wid * 4 + i;
        int row = c * 8 + sub;
        gload_lds16(Bbf + (long)(n0 + row) * K_DIM + k0 + kk, &Bs[c * 512]);
      }
    } else {
#pragma unroll
      for (int i = 0; i < 4; ++i) {  // A: fp32 load + cvt + ds_write
        int gi = i * 256 + tid;
        int row = gi >> 3, kq = (gi & 7) * 8;
        const float* px = Xf + (long)(m0 + row) * K_DIM + k0 + kq;
        f32x4 v0 = *(const f32x4*)px;
        f32x4 v1 = *(const f32x4*)(px + 4);
        u16x8 o;
        o[0] = f2bf(v0[0]); o[1] = f2bf(v0[1]); o[2] = f2bf(v0[2]); o[3] = f2bf(v0[3]);
        o[4] = f2bf(v1[0]); o[5] = f2bf(v1[1]); o[6] = f2bf(v1[2]); o[7] = f2bf(v1[3]);
        *(u16x8*)&As[row * BK + kq] = o;
      }
#pragma unroll
      for (int i = 0; i < 4; ++i) {  // B: NF4 dequant + cvt + ds_write
        int gi = i * 256 + tid;
        int row = gi >> 3, kq = (gi & 7) * 8;
        const int* pq = qw + (long)(n0 + row) * K_DIM + k0 + kq;
        i32x4 q0 = *(const i32x4*)pq;
        i32x4 q1 = *(const i32x4*)(pq + 4);
        int g = (n0 + row) * (K_DIM / 64) + t;   // quant-block index
        float s = (float)qs[g] / qf[g >> 8] + mu;
        u16x8 o;
        o[0] = f2bf(tbl[q0[0]] * s); o[1] = f2bf(tbl[q0[1]] * s);
        o[2] = f2bf(tbl[q0[2]] * s); o[3] = f2bf(tbl[q0[3]] * s);
        o[4] = f2bf(tbl[q1[0]] * s); o[5] = f2bf(tbl[q1[1]] * s);
        o[6] = f2bf(tbl[q1[2]] * s); o[7] = f2bf(tbl[q1[3]] * s);
        *(u16x8*)&Bs[row * BK + kq] = o;
      }
    }
    __syncthreads();                 // staged tile visible (vmcnt/lgkm drained)

    bf16x8 af[4][2], bfr[4][2];
#pragma unroll
    for (int i = 0; i < 4; ++i)
#pragma unroll
      for (int h = 0; h < 2; ++h) {
        af[i][h]  = *(const bf16x8*)&As[(wr * 64 + i * 16 + r16) * BK + h * 32 + hi * 8];
        bfr[i][h] = *(const bf16x8*)&Bs[(wc * 64 + i * 16 + r16) * BK + h * 32 + hi * 8];
      }
#pragma unroll
    for (int i = 0; i < 4; ++i)
#pragma unroll
      for (int j = 0; j < 4; ++j) {
        acc[i][j] = __builtin_amdgcn_mfma_f32_16x16x32_bf16(af[i][0], bfr[j][0], acc[i][j], 0, 0, 0);
        acc[i][j] = __builtin_amdgcn_mfma_f32_16x16x32_bf16(af[i][1], bfr[j][1], acc[i][j], 0, 0, 0);
      }
  }

  // epilogue: C/D layout col=lane&15, row=(lane>>4)*4+reg (m89-verified)
  const int crow = m0 + wr * 64 + hi * 4;
  const int ccol = n0 + wc * 64 + r16;
#pragma unroll
  for (int i = 0; i < 4; ++i)
#pragma unroll
    for (int j = 0; j < 4; ++j)
#pragma unroll
      for (int r = 0; r < 4; ++r)
        C[(long)(crow + i * 16 + r) * N_DIM + (ccol + j * 16)] = acc[i][j][r];
}

extern "C" void kernel_launch(void* const* d_in, const int* in_sizes, int n_in,
                              void* d_out, int out_size, void* d_ws, size_t ws_size,
                              hipStream_t stream) {
  const float* x    = (const float*)d_in[0];
  const int*   qw   = (const int*)d_in[1];
  const int*   qs   = (const int*)d_in[2];
  const float* qf   = (const float*)d_in[3];
  const float* mean = (const float*)d_in[4];
  float* out = (float*)d_out;

  const size_t xb_bytes = (size_t)M_ROWS * K_DIM * 2;  // 64 MiB
  const size_t wb_bytes = (size_t)N_DIM * K_DIM * 2;   // 86 MiB

  if (ws_size >= xb_bytes + wb_bytes) {
    unsigned short* xb = (unsigned short*)d_ws;
    unsigned short* wb = (unsigned short*)((char*)d_ws + xb_bytes);
    convert_x_kernel<<<4096, 256, 0, stream>>>(x, xb);
    dequant_w_kernel<<<4096, 256, 0, stream>>>(qw, qs, qf, mean, wb);
    gemm_nf4<0><<<NWG, 256, 0, stream>>>(xb, wb, x, qw, qs, qf, mean, out);
  } else {
    gemm_nf4<1><<<NWG, 256, 0, stream>>>(nullptr, nullptr, x, qw, qs, qf, mean, out);
  }
}

// Round 2
// 797.707 us; speedup vs baseline: 1.7684x; 1.7684x over previous
//
#include <hip/hip_runtime.h>
#include <stdint.h>

#define M_ROWS 8192
#define K_DIM  4096
#define N_DIM  11008
#define KSTEPS (K_DIM / 64)      // 64 K-tiles of BK=64

// ---- 256x256 8-phase geometry ----
#define BM 256
#define BN 256
#define MBLKS (M_ROWS / BM)      // 32
#define NBLKS (N_DIM / BN)       // 43
#define NWG   (MBLKS * NBLKS)    // 1376  (%8 == 0 -> simple XCD swizzle bijective)

typedef __attribute__((ext_vector_type(4))) float          f32x4;
typedef __attribute__((ext_vector_type(8))) __bf16         bf16x8;
typedef __attribute__((ext_vector_type(4))) int            i32x4;
typedef __attribute__((ext_vector_type(8))) unsigned short u16x8;

__constant__ float NF4_TBL[16] = {
    -1.0f, -0.6961928009986877f, -0.5250730514526367f, -0.39491748809814453f,
    -0.28444138169288635f, -0.18477343022823334f, -0.10644006729125977f,
    -0.029167551919817924f, 0.0f, 0.07958029955625534f, 0.16093020141124725f,
    0.24611230194568634f, 0.33791524171829224f, 0.44070982933044434f,
    0.5626170039176941f, 0.7229568362236023f};

__device__ __forceinline__ unsigned short f2bf(float f) {
  uint32_t u = __float_as_uint(f);
  u += 0x7fffu + ((u >> 16) & 1u);   // RNE
  return (unsigned short)(u >> 16);
}

__device__ __forceinline__ void gload_lds16(const void* g, const void* l) {
  __builtin_amdgcn_global_load_lds(
      (const __attribute__((address_space(1))) void*)(uintptr_t)g,
      (__attribute__((address_space(3))) void*)(uint32_t)(uintptr_t)l,
      16, 0, 0);
}

// ---------------- prep 1: x fp32 -> bf16 ----------------
__global__ void convert_x_kernel(const float* __restrict__ x,
                                 unsigned short* __restrict__ xb) {
  const long n8 = (long)M_ROWS * K_DIM / 8;
  for (long t = (long)blockIdx.x * blockDim.x + threadIdx.x; t < n8;
       t += (long)gridDim.x * blockDim.x) {
    const float* p = x + t * 8;
    f32x4 v0 = *(const f32x4*)p;
    f32x4 v1 = *(const f32x4*)(p + 4);
    u16x8 o;
    o[0] = f2bf(v0[0]); o[1] = f2bf(v0[1]); o[2] = f2bf(v0[2]); o[3] = f2bf(v0[3]);
    o[4] = f2bf(v1[0]); o[5] = f2bf(v1[1]); o[6] = f2bf(v1[2]); o[7] = f2bf(v1[3]);
    *(u16x8*)(xb + t * 8) = o;
  }
}

// ---------------- prep 2: NF4 dequant W -> bf16 ----------------
__global__ void dequant_w_kernel(const int* __restrict__ qw,
                                 const int* __restrict__ qs,
                                 const float* __restrict__ qf,
                                 const float* __restrict__ mean,
                                 unsigned short* __restrict__ wb) {
  __shared__ float tbl[16];
  if (threadIdx.x < 16) tbl[threadIdx.x] = NF4_TBL[threadIdx.x];
  __syncthreads();
  const float mu = mean[0];
  const long n8 = (long)N_DIM * K_DIM / 8;
  for (long t = (long)blockIdx.x * blockDim.x + threadIdx.x; t < n8;
       t += (long)gridDim.x * blockDim.x) {
    long f = t * 8;
    int  g = (int)(f >> 6);
    float s = (float)qs[g] / qf[g >> 8] + mu;
    i32x4 q0 = *(const i32x4*)(qw + f);
    i32x4 q1 = *(const i32x4*)(qw + f + 4);
    u16x8 o;
    o[0] = f2bf(tbl[q0[0]] * s); o[1] = f2bf(tbl[q0[1]] * s);
    o[2] = f2bf(tbl[q0[2]] * s); o[3] = f2bf(tbl[q0[3]] * s);
    o[4] = f2bf(tbl[q1[0]] * s); o[5] = f2bf(tbl[q1[1]] * s);
    o[6] = f2bf(tbl[q1[2]] * s); o[7] = f2bf(tbl[q1[3]] * s);
    *(u16x8*)(wb + f) = o;
  }
}

// ---------------- 256x256 8-phase bf16 GEMM:  C = A[M,K] * B[N,K]^T ----------------
// 8 waves (2M x 4N), per-wave output 128x64. LDS 128 KiB: A[2][256][64] + B[2][256][64],
// double-buffered by K-tile parity. Per K-tile 4 phases; stage order:
//   p0: B(t+1)h0 -> other buf   p1: B(t+1)h1 -> other buf
//   p2: A(t+2)h0 -> cur buf     p3: A(t+2)h1 -> cur buf
// Clobber safety: A(t) LDS reads all issue in p0/p1 (A-frags held in regs for p2/p3),
// complete before p1-end barrier => p2/p3 stages into cur-A safe. B(t) read p0/p2 but
// B stages go to the other buffer. One counted s_waitcnt vmcnt(4) per K-tile (= last
// 2 A half-tiles allowed in flight); arrival ledger: at tile t+1 p0 everything except
// A(t+3) halves has landed.
// T2 swizzle: LDS linear dest, inverse-swizzled global source chunk c^(row&7),
// ds_read at kb ^ ((row&7)<<4)  -> 2-way residual conflict (free).
#define STG(GP, LB)                                                              \
  gload_lds16((GP) + (long)srow * K_DIM + scol, &LDSbuf[(LB) + wid * 1024]);     \
  gload_lds16((GP) + (long)(64 + srow) * K_DIM + scol,                           \
              &LDSbuf[(LB) + 8192 + wid * 1024]);

__global__ __launch_bounds__(512, 2) void gemm_8phase(
    const unsigned short* __restrict__ xb, const unsigned short* __restrict__ wb,
    float* __restrict__ C) {
  __align__(16) __shared__ unsigned char LDSbuf[131072];

  const int tid = threadIdx.x;
  const int wid = tid >> 6, lane = tid & 63;
  const int wr = wid >> 2, wc = wid & 3;
  const int r16 = lane & 15, hi = lane >> 4;

  // XCD-aware bijective swizzle (NWG % 8 == 0)
  const int wg = ((int)blockIdx.x & 7) * (NWG / 8) + ((int)blockIdx.x >> 3);
  const int mb = wg % MBLKS, nb = wg / MBLKS;
  const long m0g = (long)mb * BM, n0g = (long)nb * BN;

  // staging coords (per lane)
  const int srow = wid * 8 + (lane >> 3);
  const int scol = ((lane & 7) ^ (lane >> 3)) * 8;   // inverse-swizzled source chunk

  // ds_read coords
  const int aoff = (wr * 128 + r16) * 128;           // + m*2048 (+ dbuf*32768)
  const int boff = (wc * 64 + r16) * 128;            // + n*2048 (+ 65536 + dbuf*32768)
  const int kswz0 = ((hi ^ (r16 & 7)) << 4);
  const int kswz1 = kswz0 ^ 64;

  // ---- prologue: A(0)h0,h1  B(0)h0,h1  A(1)h0,h1 ; wait all but A(1) halves ----
  STG(xb + m0g * K_DIM,               0);
  STG(xb + (m0g + 128) * K_DIM,       16384);
  STG(wb + n0g * K_DIM,               65536);
  STG(wb + (n0g + 128) * K_DIM,       65536 + 16384);
  STG(xb + m0g * K_DIM + 64,          32768);
  STG(xb + (m0g + 128) * K_DIM + 64,  32768 + 16384);
  asm volatile("s_waitcnt vmcnt(4)");
  __builtin_amdgcn_sched_barrier(0);
  __builtin_amdgcn_s_barrier();

  bf16x8 af[8][2], bq[2][2];
  f32x4 acc[8][4] = {};

  for (int t = 0; t < KSTEPS; ++t) {
    const int cur = t & 1;
    const int cA = cur * 32768, cB = 65536 + cur * 32768;
    const int nB = 65536 + (cur ^ 1) * 32768;
    const long kB = (long)((t + 1 < KSTEPS ? t + 1 : KSTEPS - 1) * 64);
    const long kA = (long)((t + 2 < KSTEPS ? t + 2 : KSTEPS - 1) * 64);

    // ---------- phase 0: A m0-3, B n0-1 ----------
#pragma unroll
    for (int m = 0; m < 4; ++m) {
      af[m][0] = *(const bf16x8*)&LDSbuf[cA + aoff + m * 2048 + kswz0];
      af[m][1] = *(const bf16x8*)&LDSbuf[cA + aoff + m * 2048 + kswz1];
    }
#pragma unroll
    for (int n = 0; n < 2; ++n) {
      bq[n][0] = *(const bf16x8*)&LDSbuf[cB + boff + n * 2048 + kswz0];
      bq[n][1] = *(const bf16x8*)&LDSbuf[cB + boff + n * 2048 + kswz1];
    }
    STG(wb + n0g * K_DIM + kB, nB);
    __builtin_amdgcn_s_barrier();
    asm volatile("s_waitcnt lgkmcnt(0)");
    __builtin_amdgcn_sched_barrier(0);
    __builtin_amdgcn_s_setprio(1);
#pragma unroll
    for (int m = 0; m < 4; ++m)
#pragma unroll
      for (int n = 0; n < 2; ++n) {
        acc[m][n] = __builtin_amdgcn_mfma_f32_16x16x32_bf16(af[m][0], bq[n][0], acc[m][n], 0, 0, 0);
        acc[m][n] = __builtin_amdgcn_mfma_f32_16x16x32_bf16(af[m][1], bq[n][1], acc[m][n], 0, 0, 0);
      }
    __builtin_amdgcn_s_setprio(0);
    __builtin_amdgcn_s_barrier();
    __builtin_amdgcn_sched_barrier(0);

    // ---------- phase 1: A m4-7 ----------
#pragma unroll
    for (int m = 4; m < 8; ++m) {
      af[m][0] = *(const bf16x8*)&LDSbuf[cA + aoff + m * 2048 + kswz0];
      af[m][1] = *(const bf16x8*)&LDSbuf[cA + aoff + m * 2048 + kswz1];
    }
    STG(wb + (n0g + 128) * K_DIM + kB, nB + 16384);
    __builtin_amdgcn_s_barrier();
    asm volatile("s_waitcnt lgkmcnt(0)");
    __builtin_amdgcn_sched_barrier(0);
    __builtin_amdgcn_s_setprio(1);
#pragma unroll
    for (int m = 4; m < 8; ++m)
#pragma unroll
      for (int n = 0; n < 2; ++n) {
        acc[m][n] = __builtin_amdgcn_mfma_f32_16x16x32_bf16(af[m][0], bq[n][0], acc[m][n], 0, 0, 0);
        acc[m][n] = __builtin_amdgcn_mfma_f32_16x16x32_bf16(af[m][1], bq[n][1], acc[m][n], 0, 0, 0);
      }
    __builtin_amdgcn_s_setprio(0);
    __builtin_amdgcn_s_barrier();
    __builtin_amdgcn_sched_barrier(0);

    // ---------- phase 2: B n2-3 (A m0-3 from regs) ----------
#pragma unroll
    for (int n = 0; n < 2; ++n) {
      bq[n][0] = *(const bf16x8*)&LDSbuf[cB + boff + (2 + n) * 2048 + kswz0];
      bq[n][1] = *(const bf16x8*)&LDSbuf[cB + boff + (2 + n) * 2048 + kswz1];
    }
    STG(xb + m0g * K_DIM + kA, cA);
    __builtin_amdgcn_s_barrier();
    asm volatile("s_waitcnt lgkmcnt(0)");
    __builtin_amdgcn_sched_barrier(0);
    __builtin_amdgcn_s_setprio(1);
#pragma unroll
    for (int m = 0; m < 4; ++m)
#pragma unroll
      for (int n = 0; n < 2; ++n) {
        acc[m][2 + n] = __builtin_amdgcn_mfma_f32_16x16x32_bf16(af[m][0], bq[n][0], acc[m][2 + n], 0, 0, 0);
        acc[m][2 + n] = __builtin_amdgcn_mfma_f32_16x16x32_bf16(af[m][1], bq[n][1], acc[m][2 + n], 0, 0, 0);
      }
    __builtin_amdgcn_s_setprio(0);
    __builtin_amdgcn_s_barrier();
    __builtin_amdgcn_sched_barrier(0);

    // ---------- phase 3: A m4-7 x B n2-3 (all from regs) ----------
    STG(xb + (m0g + 128) * K_DIM + kA, cA + 16384);
    __builtin_amdgcn_s_barrier();
    asm volatile("s_waitcnt lgkmcnt(0)");
    __builtin_amdgcn_sched_barrier(0);
    __builtin_amdgcn_s_setprio(1);
#pragma unroll
    for (int m = 4; m < 8; ++m)
#pragma unroll
      for (int n = 0; n < 2; ++n) {
        acc[m][2 + n] = __builtin_amdgcn_mfma_f32_16x16x32_bf16(af[m][0], bq[n][0], acc[m][2 + n], 0, 0, 0);
        acc[m][2 + n] = __builtin_amdgcn_mfma_f32_16x16x32_bf16(af[m][1], bq[n][1], acc[m][2 + n], 0, 0, 0);
      }
    __builtin_amdgcn_s_setprio(0);
    asm volatile("s_waitcnt vmcnt(4)");   // counted: only A(t+2) halves may remain in flight
    __builtin_amdgcn_sched_barrier(0);
    __builtin_amdgcn_s_barrier();
    __builtin_amdgcn_sched_barrier(0);
  }

  // ---- epilogue: C/D layout col=lane&15, row=hi*4+reg; nontemporal (no L3 thrash) ----
  const long crow = m0g + wr * 128 + hi * 4;
  const long ccol = n0g + wc * 64 + r16;
#pragma unroll
  for (int m = 0; m < 8; ++m)
#pragma unroll
    for (int n = 0; n < 4; ++n)
#pragma unroll
      for (int r = 0; r < 4; ++r)
        __builtin_nontemporal_store(
            acc[m][n][r], &C[(crow + m * 16 + r) * N_DIM + ccol + n * 16]);
}

// ---------------- fallback (no workspace): fused 128^2 kernel from round 1 ----------------
__global__ __launch_bounds__(256) void gemm_fallback(
    const float* __restrict__ Xf, const int* __restrict__ qw,
    const int* __restrict__ qs, const float* __restrict__ qf,
    const float* __restrict__ meanp, float* __restrict__ C) {
  __shared__ unsigned short As[128 * 64];
  __shared__ unsigned short Bs[128 * 64];
  __shared__ float tbl[16];
  const int tid = threadIdx.x;
  if (tid < 16) tbl[tid] = NF4_TBL[tid];
  const float mu = meanp[0];
  const int nwg = (M_ROWS / 128) * (N_DIM / 128);
  const int wg = ((int)blockIdx.x & 7) * (nwg / 8) + ((int)blockIdx.x >> 3);
  const int mb = wg % (M_ROWS / 128), nb = wg / (M_ROWS / 128);
  const int m0 = mb * 128, n0 = nb * 128;
  const int wid = tid >> 6, lane = tid & 63;
  const int wr = wid >> 1, wcc = wid & 1;
  const int r16 = lane & 15, hi = lane >> 4;
  f32x4 acc[4][4] = {};
  for (int t = 0; t < KSTEPS; ++t) {
    const int k0 = t * 64;
    __syncthreads();
#pragma unroll
    for (int i = 0; i < 4; ++i) {
      int gi = i * 256 + tid;
      int row = gi >> 3, kq = (gi & 7) * 8;
      const float* px = Xf + (long)(m0 + row) * K_DIM + k0 + kq;
      f32x4 v0 = *(const f32x4*)px;
      f32x4 v1 = *(const f32x4*)(px + 4);
      u16x8 o;
      o[0] = f2bf(v0[0]); o[1] = f2bf(v0[1]); o[2] = f2bf(v0[2]); o[3] = f2bf(v0[3]);
      o[4] = f2bf(v1[0]); o[5] = f2bf(v1[1]); o[6] = f2bf(v1[2]); o[7] = f2bf(v1[3]);
      *(u16x8*)&As[row * 64 + kq] = o;
    }
#pragma unroll
    for (int i = 0; i < 4; ++i) {
      int gi = i * 256 + tid;
      int row = gi >> 3, kq = (gi & 7) * 8;
      const int* pq = qw + (long)(n0 + row) * K_DIM + k0 + kq;
      i32x4 q0 = *(const i32x4*)pq;
      i32x4 q1 = *(const i32x4*)(pq + 4);
      int g = (n0 + row) * (K_DIM / 64) + t;
      float s = (float)qs[g] / qf[g >> 8] + mu;
      u16x8 o;
      o[0] = f2bf(tbl[q0[0]] * s); o[1] = f2bf(tbl[q0[1]] * s);
      o[2] = f2bf(tbl[q0[2]] * s); o[3] = f2bf(tbl[q0[3]] * s);
      o[4] = f2bf(tbl[q1[0]] * s); o[5] = f2bf(tbl[q1[1]] * s);
      o[6] = f2bf(tbl[q1[2]] * s); o[7] = f2bf(tbl[q1[3]] * s);
      *(u16x8*)&Bs[row * 64 + kq] = o;
    }
    __syncthreads();
    bf16x8 afr[4][2], bfr[4][2];
#pragma unroll
    for (int i = 0; i < 4; ++i)
#pragma unroll
      for (int h = 0; h < 2; ++h) {
        afr[i][h] = *(const bf16x8*)&As[(wr * 64 + i * 16 + r16) * 64 + h * 32 + hi * 8];
        bfr[i][h] = *(const bf16x8*)&Bs[(wcc * 64 + i * 16 + r16) * 64 + h * 32 + hi * 8];
      }
#pragma unroll
    for (int i = 0; i < 4; ++i)
#pragma unroll
      for (int j = 0; j < 4; ++j) {
        acc[i][j] = __builtin_amdgcn_mfma_f32_16x16x32_bf16(afr[i][0], bfr[j][0], acc[i][j], 0, 0, 0);
        acc[i][j] = __builtin_amdgcn_mfma_f32_16x16x32_bf16(afr[i][1], bfr[j][1], acc[i][j], 0, 0, 0);
      }
  }
  const int crow = m0 + wr * 64 + hi * 4;
  const int ccol = n0 + wcc * 64 + r16;
#pragma unroll
  for (int i = 0; i < 4; ++i)
#pragma unroll
    for (int j = 0; j < 4; ++j)
#pragma unroll
      for (int r = 0; r < 4; ++r)
        C[(long)(crow + i * 16 + r) * N_DIM + (ccol + j * 16)] = acc[i][j][r];
}

extern "C" void kernel_launch(void* const* d_in, const int* in_sizes, int n_in,
                              void* d_out, int out_size, void* d_ws, size_t ws_size,
                              hipStream_t stream) {
  const float* x    = (const float*)d_in[0];
  const int*   qw   = (const int*)d_in[1];
  const int*   qs   = (const int*)d_in[2];
  const float* qf   = (const float*)d_in[3];
  const float* mean = (const float*)d_in[4];
  float* out = (float*)d_out;

  const size_t xb_bytes = (size_t)M_ROWS * K_DIM * 2;  // 64 MiB
  const size_t wb_bytes = (size_t)N_DIM * K_DIM * 2;   // 86 MiB

  if (ws_size >= xb_bytes + wb_bytes) {
    unsigned short* xb = (unsigned short*)d_ws;
    unsigned short* wb = (unsigned short*)((char*)d_ws + xb_bytes);
    convert_x_kernel<<<4096, 256, 0, stream>>>(x, xb);
    dequant_w_kernel<<<4096, 256, 0, stream>>>(qw, qs, qf, mean, wb);
    gemm_8phase<<<NWG, 512, 0, stream>>>(xb, wb, out);
  } else {
    gemm_fallback<<<(M_ROWS / 128) * (N_DIM / 128), 256, 0, stream>>>(
        x, qw, qs, qf, mean, out);
  }
}